// Round 3
// baseline (960.798 us; speedup 1.0000x reference)
//
#include <hip/hip_runtime.h>
#include <hip/hip_bf16.h>
#include <math.h>

// Problem constants
#define PB 16      // batches
#define PN 32768   // points
#define PD 256     // point feature dim
#define PE 512     // embed dim
#define PH 8       // heads
#define PK 512     // top-k
#define PT 16      // output tokens
#define DH 64      // head dim

typedef __attribute__((ext_vector_type(8))) short bf16x8;
typedef __attribute__((ext_vector_type(4))) float f32x4;

__device__ __forceinline__ unsigned short f2bf(float f) {
    __hip_bfloat16 h = __float2bfloat16(f);
    return *(unsigned short*)&h;
}
__device__ __forceinline__ float b2f(unsigned short u) {
    return __uint_as_float(((unsigned int)u) << 16);
}

// ---------------------------------------------------------------------------
// Kernel 1: per-batch top-512 (radix select on monotone u32 keys) + bitonic
// sort by (key desc, idx asc). Parallel LDS suffix-scan digit find.
// ---------------------------------------------------------------------------
__global__ __launch_bounds__(512) void topk_kernel(const float* __restrict__ scores,
                                                   int* __restrict__ sorted_idx) {
    const int b = blockIdx.x;
    const int tid = threadIdx.x;
    const int NT = 512;
    const float* s = scores + (size_t)b * PN;

    __shared__ unsigned int hist[256];
    __shared__ unsigned int scan_buf[256];
    __shared__ unsigned int sh_prefix;
    __shared__ int sh_remaining;
    __shared__ unsigned int sh_cnt_gt, sh_cnt_eq;
    __shared__ unsigned long long comp[PK];
    __shared__ unsigned int eq_idx[PK];

    unsigned int prefix = 0;
    int remaining = PK;
    for (int shift = 24; shift >= 0; shift -= 8) {
        for (int i = tid; i < 256; i += NT) hist[i] = 0;
        __syncthreads();
        for (int i = tid * 4; i < PN; i += NT * 4) {
            float4 f = *(const float4*)(s + i);
            const float* fp = (const float*)&f;
#pragma unroll
            for (int j = 0; j < 4; ++j) {
                unsigned int u = __float_as_uint(fp[j]);
                u = (u & 0x80000000u) ? ~u : (u | 0x80000000u);
                bool ok = (shift == 24) || ((u >> (shift + 8)) == prefix);
                if (ok) atomicAdd(&hist[(u >> shift) & 0xFFu], 1u);
            }
        }
        __syncthreads();
        // parallel suffix-sum over the 256 bins
        if (tid < 256) scan_buf[tid] = hist[tid];
        __syncthreads();
        for (int off = 1; off < 256; off <<= 1) {
            unsigned int add = 0;
            if (tid < 256 - off) add = scan_buf[tid + off];
            __syncthreads();
            if (tid < 256) scan_buf[tid] += add;
            __syncthreads();
        }
        if (tid < 256) {
            int suf = (int)scan_buf[tid];
            int sufn = (tid < 255) ? (int)scan_buf[tid + 1] : 0;
            if (suf >= remaining && sufn < remaining) {  // exactly one tid
                sh_prefix = (prefix << 8) | (unsigned)tid;
                sh_remaining = remaining - sufn;
            }
        }
        __syncthreads();
        prefix = sh_prefix;
        remaining = sh_remaining;
        __syncthreads();
    }
    const unsigned int TKEY = prefix;

    if (tid == 0) { sh_cnt_gt = 0; sh_cnt_eq = 0; }
    __syncthreads();
    for (int i = tid * 4; i < PN; i += NT * 4) {
        float4 f = *(const float4*)(s + i);
        const float* fp = (const float*)&f;
#pragma unroll
        for (int j = 0; j < 4; ++j) {
            unsigned int u = __float_as_uint(fp[j]);
            u = (u & 0x80000000u) ? ~u : (u | 0x80000000u);
            if (u > TKEY) {
                unsigned p = atomicAdd(&sh_cnt_gt, 1u);
                comp[p] = ((unsigned long long)u << 32) | (unsigned int)(~(unsigned)(i + j));
            } else if (u == TKEY) {
                unsigned p = atomicAdd(&sh_cnt_eq, 1u);
                if (p < PK) eq_idx[p] = (unsigned)(i + j);
            }
        }
    }
    __syncthreads();
    const int cnt_gt = (int)sh_cnt_gt;
    const int need_eq = PK - cnt_gt;
    const int ec = (int)sh_cnt_eq < PK ? (int)sh_cnt_eq : PK;
    if (tid == 0) {
        for (int j = 0; j < need_eq; ++j) {
            unsigned mv = 0xFFFFFFFFu; int mb = 0;
            for (int i2 = 0; i2 < ec; ++i2)
                if (eq_idx[i2] < mv) { mv = eq_idx[i2]; mb = i2; }
            comp[cnt_gt + j] = ((unsigned long long)TKEY << 32) | (unsigned int)(~mv);
            eq_idx[mb] = 0xFFFFFFFFu;
        }
    }
    __syncthreads();

    // bitonic sort, descending (key desc; tie -> ~idx larger = idx smaller first)
    for (unsigned ksz = 2; ksz <= PK; ksz <<= 1) {
        for (unsigned j = ksz >> 1; j > 0; j >>= 1) {
            unsigned i = (unsigned)tid;
            unsigned ixj = i ^ j;
            if (ixj > i && i < PK) {
                unsigned long long a = comp[i], c = comp[ixj];
                bool sw = ((i & ksz) == 0) ? (a < c) : (a > c);
                if (sw) { comp[i] = c; comp[ixj] = a; }
            }
            __syncthreads();
        }
    }
    if (tid < PK)
        sorted_idx[b * PK + tid] = (int)(~(unsigned int)(comp[tid] & 0xFFFFFFFFull));
}

// ---------------------------------------------------------------------------
// Kernel 2 ("prep"): one dispatch, three independent jobs routed by blockIdx:
//   blocks [0,2048):    gather rows -> Ag bf16 [8192,256]; t<16 rows also
//                       to Aq fp32 [256,256]
//   blocks [2048,2304): Wc = Wkv @ proj_w  (fp32, [1024,256]) -> bf16 Wc16
//   blocks [2304,2368): b_comb = Wkv @ proj_b + in_b[kv part]  [1024] fp32
// ---------------------------------------------------------------------------
__global__ __launch_bounds__(256) void prep_kernel(
    const float* __restrict__ feats, const int* __restrict__ sidx,
    const float* __restrict__ proj_w, const float* __restrict__ proj_b,
    const float* __restrict__ in_w, const float* __restrict__ in_b,
    __hip_bfloat16* __restrict__ Ag, float* __restrict__ Aq,
    __hip_bfloat16* __restrict__ Wc16, float* __restrict__ b_comb) {
    const int blk = blockIdx.x;
    const int tid = threadIdx.x;
    __shared__ float As[32][33];
    __shared__ float Bs[32][33];

    if (blk < 2048) {
        // ---- gather: 4 rows per block, float4 per lane ----
        const int row = blk * 4 + (tid >> 6);
        const int lane = tid & 63;
        const int b = row >> 9, t = row & (PK - 1);
        const int src = sidx[row];
        float4 f = *(const float4*)(feats + ((size_t)b * PN + (size_t)src) * PD + lane * 4);
        ushort4 u;
        u.x = f2bf(f.x); u.y = f2bf(f.y); u.z = f2bf(f.z); u.w = f2bf(f.w);
        *(ushort4*)((unsigned short*)Ag + (size_t)row * PD + lane * 4) = u;
        if (t < PT)
            *(float4*)(Aq + (size_t)(b * PT + t) * PD + lane * 4) = f;
    } else if (blk < 2048 + 256) {
        // ---- compose_w: C[1024,256] = Wkv[1024,512] @ P[512,256] (NN) ----
        const int bb = blk - 2048;
        const int m0 = (bb >> 3) * 32, n0 = (bb & 7) * 32;
        const float* A = in_w + (size_t)PE * PE;   // Wkv
        const int tx = tid & 15, ty = tid >> 4;
        float a00 = 0, a01 = 0, a10 = 0, a11 = 0;
        for (int k0 = 0; k0 < PE; k0 += 32) {
            for (int e = tid; e < 1024; e += 256) {
                int r = e >> 5, c = e & 31;
                As[r][c] = A[(size_t)(m0 + r) * PE + k0 + c];
                Bs[r][c] = proj_w[(size_t)(k0 + r) * PD + n0 + c];
            }
            __syncthreads();
#pragma unroll
            for (int kk = 0; kk < 32; ++kk) {
                float x0 = As[ty * 2][kk], x1 = As[ty * 2 + 1][kk];
                float y0 = Bs[kk][tx * 2], y1 = Bs[kk][tx * 2 + 1];
                a00 += x0 * y0; a01 += x0 * y1;
                a10 += x1 * y0; a11 += x1 * y1;
            }
            __syncthreads();
        }
        __hip_bfloat16* W = Wc16;
        W[(size_t)(m0 + ty * 2) * PD + n0 + tx * 2]         = __float2bfloat16(a00);
        W[(size_t)(m0 + ty * 2) * PD + n0 + tx * 2 + 1]     = __float2bfloat16(a01);
        W[(size_t)(m0 + ty * 2 + 1) * PD + n0 + tx * 2]     = __float2bfloat16(a10);
        W[(size_t)(m0 + ty * 2 + 1) * PD + n0 + tx * 2 + 1] = __float2bfloat16(a11);
    } else {
        // ---- b_comb[1024] = Wkv @ proj_b + in_b[512..1535] ----
        const int bi = blk - 2304;              // 0..63, 16 rows each
        const int rr = tid >> 4, ko = tid & 15;
        const int row = bi * 16 + rr;
        const float* wrow = in_w + (size_t)PE * PE + (size_t)row * PE;
        float acc = 0;
#pragma unroll
        for (int c = 0; c < 8; ++c) {
            int e = c * 64 + ko * 4;
            float4 w4 = *(const float4*)(wrow + e);
            float4 b4 = *(const float4*)(proj_b + e);
            acc += w4.x * b4.x + w4.y * b4.y + w4.z * b4.z + w4.w * b4.w;
        }
#pragma unroll
        for (int sft = 8; sft >= 1; sft >>= 1) acc += __shfl_xor(acc, sft, 16);
        if (ko == 0) b_comb[row] = acc + in_b[PE + row];
    }
}

// ---------------------------------------------------------------------------
// Kernel 3: bf16 MFMA GEMM, C16[M,N] = A[M,K]*B[N,K]^T + bias (bf16 out).
// Block 256 thr = 4 waves (2x2), wave tile 64x64, block tile 128x128.
// ---------------------------------------------------------------------------
__global__ __launch_bounds__(256) void gemm_bt_bf16_kernel(
    const short* __restrict__ A, const short* __restrict__ Bm,
    const float* __restrict__ bias, __hip_bfloat16* __restrict__ C16,
    int M, int N, int Kd) {
    const int tid = threadIdx.x;
    const int wave = tid >> 6;
    const int lane = tid & 63;
    const int m0 = blockIdx.x * 128 + (wave >> 1) * 64;
    const int n0 = blockIdx.y * 128 + (wave & 1) * 64;
    const int mrow = lane & 15;
    const int quad = lane >> 4;

    f32x4 acc[4][4] = {};
    for (int k0 = 0; k0 < Kd; k0 += 32) {
        const int kk = k0 + quad * 8;
        bf16x8 a[4], bf[4];
#pragma unroll
        for (int i = 0; i < 4; ++i)
            a[i] = *(const bf16x8*)(A + (size_t)(m0 + i * 16 + mrow) * Kd + kk);
#pragma unroll
        for (int i = 0; i < 4; ++i)
            bf[i] = *(const bf16x8*)(Bm + (size_t)(n0 + i * 16 + mrow) * Kd + kk);
#pragma unroll
        for (int i = 0; i < 4; ++i)
#pragma unroll
            for (int j = 0; j < 4; ++j)
                acc[i][j] = __builtin_amdgcn_mfma_f32_16x16x32_bf16(a[i], bf[j], acc[i][j], 0, 0, 0);
    }
#pragma unroll
    for (int i = 0; i < 4; ++i)
#pragma unroll
        for (int j = 0; j < 4; ++j)
#pragma unroll
            for (int r = 0; r < 4; ++r) {
                int row = m0 + i * 16 + quad * 4 + r;
                int col = n0 + j * 16 + mrow;
                C16[(size_t)row * N + col] = __float2bfloat16(acc[i][j][r] + bias[col]);
            }
}

// ---------------------------------------------------------------------------
// Kernel 4: fp32 tiled GEMM, C[M,N] = A[M,K]*B[N,K]^T + bias, optional fused
// exact-GELU + residual epilogue (resid != nullptr):  C = resid + gelu(acc+b)
// ---------------------------------------------------------------------------
__global__ __launch_bounds__(256) void sgemm_bt_kernel(
    const float* __restrict__ A, const float* __restrict__ Bm,
    const float* __restrict__ bias, const float* __restrict__ resid,
    float* __restrict__ C, int M, int N, int Kd) {
    __shared__ float As[32][33];
    __shared__ float Bs[32][33];
    const int tid = threadIdx.x;
    const int m0 = blockIdx.x * 32, n0 = blockIdx.y * 32;
    const int tx = tid & 15, ty = tid >> 4;
    float acc00 = 0, acc01 = 0, acc10 = 0, acc11 = 0;
    for (int k0 = 0; k0 < Kd; k0 += 32) {
        for (int e = tid; e < 1024; e += 256) {
            int r = e >> 5, c = e & 31;
            As[r][c] = A[(size_t)(m0 + r) * Kd + k0 + c];
            Bs[r][c] = Bm[(size_t)(n0 + r) * Kd + k0 + c];
        }
        __syncthreads();
#pragma unroll
        for (int kk = 0; kk < 32; ++kk) {
            float a0 = As[ty * 2][kk], a1 = As[ty * 2 + 1][kk];
            float b0 = Bs[tx * 2][kk], b1 = Bs[tx * 2 + 1][kk];
            acc00 += a0 * b0; acc01 += a0 * b1;
            acc10 += a1 * b0; acc11 += a1 * b1;
        }
        __syncthreads();
    }
    float bc0 = bias[n0 + tx * 2], bc1 = bias[n0 + tx * 2 + 1];
    float v00 = acc00 + bc0, v01 = acc01 + bc1, v10 = acc10 + bc0, v11 = acc11 + bc1;
    size_t i00 = (size_t)(m0 + ty * 2) * N + n0 + tx * 2;
    size_t i10 = (size_t)(m0 + ty * 2 + 1) * N + n0 + tx * 2;
    if (resid) {
        v00 = resid[i00]     + 0.5f * v00 * (1.0f + erff(v00 * 0.7071067811865475f));
        v01 = resid[i00 + 1] + 0.5f * v01 * (1.0f + erff(v01 * 0.7071067811865475f));
        v10 = resid[i10]     + 0.5f * v10 * (1.0f + erff(v10 * 0.7071067811865475f));
        v11 = resid[i10 + 1] + 0.5f * v11 * (1.0f + erff(v11 * 0.7071067811865475f));
    }
    C[i00] = v00; C[i00 + 1] = v01;
    C[i10] = v10; C[i10 + 1] = v11;
}

// ---------------------------------------------------------------------------
// Kernel 5: attention with fused q-projection. One block per (b,h).
// Reads xq fp32 [256,512], in_w (q rows), in_b (q bias), kv bf16 [8192,1024].
// ---------------------------------------------------------------------------
__global__ __launch_bounds__(256) void attn_kernel(
    const float* __restrict__ xq, const float* __restrict__ in_w,
    const float* __restrict__ in_b, const __hip_bfloat16* __restrict__ kv,
    float* __restrict__ ob) {
    const int bh = blockIdx.x;
    const int b = bh >> 3, h = bh & 7;
    const int tid = threadIdx.x;
    __shared__ float xs[PT][PE + 4];
    __shared__ float qs[PT][DH + 4];
    __shared__ float ls[PT][PK + 1];

    // stage xq rows of this batch (8192 floats, 8 float4 per thread)
#pragma unroll
    for (int i = 0; i < 8; ++i) {
        int idx = tid * 4 + i * 1024;
        int t = idx >> 9, e = idx & 511;
        float4 f = *(const float4*)(xq + (size_t)(b * PT + t) * PE + e);
        *(float4*)&xs[t][e] = f;
    }
    __syncthreads();

    // q[t][d0..d0+3] = xs[t][:] . Wq[h*64+d0+j][:] + bq
    {
        const int t = tid >> 4, d0 = (tid & 15) * 4;
        const float* w0 = in_w + (size_t)(h * DH + d0) * PE;
        float a0 = 0, a1 = 0, a2 = 0, a3 = 0;
        for (int e = 0; e < PE; e += 4) {
            float4 xv = *(const float4*)&xs[t][e];
            float4 w4a = *(const float4*)(w0 + e);
            float4 w4b = *(const float4*)(w0 + PE + e);
            float4 w4c = *(const float4*)(w0 + 2 * PE + e);
            float4 w4d = *(const float4*)(w0 + 3 * PE + e);
            a0 += xv.x * w4a.x + xv.y * w4a.y + xv.z * w4a.z + xv.w * w4a.w;
            a1 += xv.x * w4b.x + xv.y * w4b.y + xv.z * w4b.z + xv.w * w4b.w;
            a2 += xv.x * w4c.x + xv.y * w4c.y + xv.z * w4c.z + xv.w * w4c.w;
            a3 += xv.x * w4d.x + xv.y * w4d.y + xv.z * w4d.z + xv.w * w4d.w;
        }
        qs[t][d0]     = a0 + in_b[h * DH + d0];
        qs[t][d0 + 1] = a1 + in_b[h * DH + d0 + 1];
        qs[t][d0 + 2] = a2 + in_b[h * DH + d0 + 2];
        qs[t][d0 + 3] = a3 + in_b[h * DH + d0 + 3];
    }
    __syncthreads();

    const int t = tid >> 4;
    const int ko = tid & 15;
    for (int k = ko; k < PK; k += 16) {
        const ushort4* kp = (const ushort4*)((const unsigned short*)kv +
                             (size_t)(b * PK + k) * (2 * PE) + h * DH);
        float acc = 0;
#pragma unroll
        for (int c = 0; c < 16; ++c) {
            ushort4 vv = kp[c];
            acc += qs[t][c * 4 + 0] * b2f(vv.x) + qs[t][c * 4 + 1] * b2f(vv.y)
                 + qs[t][c * 4 + 2] * b2f(vv.z) + qs[t][c * 4 + 3] * b2f(vv.w);
        }
        ls[t][k] = acc * 0.125f;
    }
    // softmax over row t: the 16 owning lanes are in one wave
    float m = -1e30f;
    for (int k = ko; k < PK; k += 16) m = fmaxf(m, ls[t][k]);
#pragma unroll
    for (int s = 8; s >= 1; s >>= 1) m = fmaxf(m, __shfl_xor(m, s, 16));
    float sum = 0;
    for (int k = ko; k < PK; k += 16) {
        float e = __expf(ls[t][k] - m);
        ls[t][k] = e;
        sum += e;
    }
#pragma unroll
    for (int s = 8; s >= 1; s >>= 1) sum += __shfl_xor(sum, s, 16);
    const float inv = 1.0f / sum;

    // o = attn @ v ; thread owns 4 consecutive d's -> one 8B load per k
    const int d0 = (tid & 15) * 4;
    const unsigned short* vbase = (const unsigned short*)kv +
                                  (size_t)(b * PK) * (2 * PE) + PE + h * DH + d0;
    float o0 = 0, o1 = 0, o2 = 0, o3 = 0;
#pragma unroll 4
    for (int k = 0; k < PK; ++k) {
        float w = ls[t][k];
        ushort4 vv = *(const ushort4*)(vbase + (size_t)k * (2 * PE));
        o0 += w * b2f(vv.x); o1 += w * b2f(vv.y);
        o2 += w * b2f(vv.z); o3 += w * b2f(vv.w);
    }
    float4 o; o.x = o0 * inv; o.y = o1 * inv; o.z = o2 * inv; o.w = o3 * inv;
    *(float4*)(ob + (size_t)(b * PT + t) * PE + h * DH + d0) = o;
}

// ---------------------------------------------------------------------------
// Kernel 6: y = LayerNorm(xq + o2) * g + b      (256 rows of 512)
// ---------------------------------------------------------------------------
__global__ __launch_bounds__(256) void ln_kernel(
    const float* __restrict__ xq, const float* __restrict__ o2,
    const float* __restrict__ g, const float* __restrict__ bb,
    float* __restrict__ y) {
    const int r = blockIdx.x;
    const int tid = threadIdx.x;
    __shared__ float red[4], red2[4];
    float v0 = xq[(size_t)r * PE + tid] + o2[(size_t)r * PE + tid];
    float v1 = xq[(size_t)r * PE + 256 + tid] + o2[(size_t)r * PE + 256 + tid];
    float s = v0 + v1;
#pragma unroll
    for (int sh = 32; sh >= 1; sh >>= 1) s += __shfl_xor(s, sh, 64);
    if ((tid & 63) == 0) red[tid >> 6] = s;
    __syncthreads();
    float mean = (red[0] + red[1] + red[2] + red[3]) * (1.0f / 512.0f);
    float d0 = v0 - mean, d1 = v1 - mean;
    float sq = d0 * d0 + d1 * d1;
#pragma unroll
    for (int sh = 32; sh >= 1; sh >>= 1) sq += __shfl_xor(sq, sh, 64);
    if ((tid & 63) == 0) red2[tid >> 6] = sq;
    __syncthreads();
    float var = (red2[0] + red2[1] + red2[2] + red2[3]) * (1.0f / 512.0f);
    float rs = rsqrtf(var + 1e-5f);
    y[(size_t)r * PE + tid]       = d0 * rs * g[tid] + bb[tid];
    y[(size_t)r * PE + 256 + tid] = d1 * rs * g[tid + 256] + bb[tid + 256];
}

// ---------------------------------------------------------------------------
extern "C" void kernel_launch(void* const* d_in, const int* in_sizes, int n_in,
                              void* d_out, int out_size, void* d_ws, size_t ws_size,
                              hipStream_t stream) {
    const float* feats  = (const float*)d_in[0];
    const float* scores = (const float*)d_in[1];
    const float* proj_w = (const float*)d_in[2];
    const float* proj_b = (const float*)d_in[3];
    const float* in_w   = (const float*)d_in[4];
    const float* in_b   = (const float*)d_in[5];
    const float* out_w  = (const float*)d_in[6];
    const float* out_b  = (const float*)d_in[7];
    const float* ln_g   = (const float*)d_in[8];
    const float* ln_b   = (const float*)d_in[9];
    const float* ffn_w  = (const float*)d_in[10];
    const float* ffn_b  = (const float*)d_in[11];
    float* out = (float*)d_out;

    char* p = (char*)d_ws;
    auto alloc = [&](size_t bytes) {
        void* r = (void*)p;
        p += (bytes + 255) & ~(size_t)255;
        return r;
    };
    int* sidx             = (int*)alloc((size_t)PB * PK * 4);
    __hip_bfloat16* Ag    = (__hip_bfloat16*)alloc((size_t)PB * PK * PD * 2);
    float* Aq             = (float*)alloc((size_t)PB * PT * PD * 4);
    __hip_bfloat16* Wc16  = (__hip_bfloat16*)alloc((size_t)2 * PE * PD * 2);
    float* b_comb         = (float*)alloc((size_t)2 * PE * 4);
    __hip_bfloat16* kv16  = (__hip_bfloat16*)alloc((size_t)PB * PK * 2 * PE * 2);
    float* xq             = (float*)alloc((size_t)PB * PT * PE * 4);
    float* ob             = (float*)alloc((size_t)PB * PT * PE * 4);
    float* o2             = (float*)alloc((size_t)PB * PT * PE * 4);
    float* yb             = (float*)alloc((size_t)PB * PT * PE * 4);
    if ((size_t)(p - (char*)d_ws) > ws_size) return;  // workspace too small

    // 1. top-k per batch
    topk_kernel<<<PB, 512, 0, stream>>>(scores, sidx);
    // 2. prep: gather (+Aq) | Wc = Wkv@Wp -> bf16 | b_comb = Wkv@bp + bkv
    prep_kernel<<<2048 + 256 + 64, 256, 0, stream>>>(
        feats, sidx, proj_w, proj_b, in_w, in_b, Ag, Aq, Wc16, b_comb);
    // 3. kv = Ag @ Wc^T + b_comb   (M=8192, N=1024, K=256) -> kv16
    gemm_bt_bf16_kernel<<<dim3(64, 8), 256, 0, stream>>>(
        (const short*)Ag, (const short*)Wc16, b_comb, kv16, PB * PK, 2 * PE, PD);
    // 4. xq = Aq @ proj_w^T + proj_b   (M=256, N=512, K=256) fp32
    sgemm_bt_kernel<<<dim3(8, 16), 256, 0, stream>>>(Aq, proj_w, proj_b, nullptr, xq,
                                                     PB * PT, PE, PD);
    // 5. attention (q-projection fused)
    attn_kernel<<<PB * PH, 256, 0, stream>>>(xq, in_w, in_b, kv16, ob);
    // 6. o2 = o @ out_proj^T + b
    sgemm_bt_kernel<<<dim3(8, 16), 256, 0, stream>>>(ob, out_w, out_b, nullptr, o2,
                                                     PB * PT, PE, PE);
    // 7. y = LN(xq + o2)
    ln_kernel<<<PB * PT, 256, 0, stream>>>(xq, o2, ln_g, ln_b, yb);
    // 8. out = y + gelu(y @ ffn_w^T + b)  (fused epilogue, writes d_out)
    sgemm_bt_kernel<<<dim3(8, 16), 256, 0, stream>>>(yb, ffn_w, ffn_b, yb, out,
                                                     PB * PT, PE, PE);
}